// Round 1
// baseline (6019.322 us; speedup 1.0000x reference)
//
#include <hip/hip_runtime.h>
#include <math.h>

constexpr int NP = 100000, NA = 50000, NS = 5000;
constexpr int EPA = 600000, EAP = 600000, EPS = 200000, ESP = 200000;

__device__ __forceinline__ float gelu_f(float x) {
  float x3 = x*x*x;
  return 0.5f*x*(1.0f + tanhf(0.7978845608028654f*(x + 0.044715f*x3)));
}

// C[n,128] = A[n, (chunk of lda)] @ W[128,128]; flags: 1=accumulate into C, 2=bias+gelu epilogue
__global__ __launch_bounds__(256) void gemm128(
    const float* __restrict__ A, int lda,
    const float* __restrict__ W,
    float* __restrict__ C, int n,
    const float* __restrict__ bias, int flags)
{
  __shared__ float At[128][64];   // 32 KB: A tile transposed, full K=128
  __shared__ float Wl[64*128];    // 32 KB: half-K chunk of W
  const int tid = threadIdx.x;

  // stage A tile (64 rows x K=128) transposed into LDS
  {
    const int row = tid & 63, kq = tid >> 6;
    const int grow = blockIdx.x*64 + row;
    const float* Ar = A + (size_t)grow * lda;
    #pragma unroll
    for (int i = 0; i < 8; ++i) {
      const int k0 = kq*32 + i*4;
      float4 v = make_float4(0.f,0.f,0.f,0.f);
      if (grow < n) v = *(const float4*)(Ar + k0);
      At[k0+0][row] = v.x; At[k0+1][row] = v.y;
      At[k0+2][row] = v.z; At[k0+3][row] = v.w;
    }
  }

  const int rg = tid >> 4;   // 0..15 -> rows rg*4..+3
  const int cg = tid & 15;   // 0..15 -> cols cg*4..+3 and 64+cg*4..+3
  float acc[4][8];
  #pragma unroll
  for (int i=0;i<4;++i)
    #pragma unroll
    for (int j=0;j<8;++j) acc[i][j]=0.f;

  for (int kc = 0; kc < 2; ++kc) {
    __syncthreads();
    {
      const float4* W4 = (const float4*)(W + kc*64*128);
      float4* Wl4 = (float4*)Wl;
      #pragma unroll
      for (int i = 0; i < 8; ++i) Wl4[tid + i*256] = W4[tid + i*256];
    }
    __syncthreads();
    #pragma unroll 4
    for (int k = 0; k < 64; ++k) {
      const float4 a   = *(const float4*)&At[kc*64 + k][rg*4];
      const float4 wlo = *(const float4*)&Wl[k*128 + cg*4];
      const float4 whi = *(const float4*)&Wl[k*128 + 64 + cg*4];
      const float av[4] = {a.x,a.y,a.z,a.w};
      const float wl_[4] = {wlo.x,wlo.y,wlo.z,wlo.w};
      const float wh_[4] = {whi.x,whi.y,whi.z,whi.w};
      #pragma unroll
      for (int i=0;i<4;++i) {
        #pragma unroll
        for (int j=0;j<4;++j) {
          acc[i][j]   = fmaf(av[i], wl_[j], acc[i][j]);
          acc[i][j+4] = fmaf(av[i], wh_[j], acc[i][j+4]);
        }
      }
    }
  }

  const int rbase = blockIdx.x*64 + rg*4;
  #pragma unroll
  for (int i=0;i<4;++i) {
    const int r = rbase + i;
    if (r >= n) break;
    float* Cr = C + (size_t)r*128;
    #pragma unroll
    for (int h=0; h<2; ++h) {
      const int c0 = h*64 + cg*4;
      float4 v = make_float4(acc[i][h*4+0], acc[i][h*4+1], acc[i][h*4+2], acc[i][h*4+3]);
      if (flags & 1) {
        float4 old = *(const float4*)(Cr + c0);
        v.x+=old.x; v.y+=old.y; v.z+=old.z; v.w+=old.w;
      }
      if (flags & 2) {
        v.x = gelu_f(v.x + bias[c0+0]);
        v.y = gelu_f(v.y + bias[c0+1]);
        v.z = gelu_f(v.z + bias[c0+2]);
        v.w = gelu_f(v.w + bias[c0+3]);
      }
      *(float4*)(Cr + c0) = v;
    }
  }
}

__global__ void deg_count(const int* __restrict__ dst, int E, float* __restrict__ deg) {
  int e = blockIdx.x*256 + threadIdx.x;
  if (e < E) atomicAdd(&deg[dst[e]], 1.0f);
}

__global__ void recip_k(float* __restrict__ d, int n) {
  int i = blockIdx.x*256 + threadIdx.x;
  if (i < n) d[i] = 1.0f / fmaxf(d[i], 1.0f);
}

// acc[dst] += feat[src] * rdeg[dst]   (32 lanes per edge, float4 per lane)
__global__ void scatter_mean(const float* __restrict__ feat,
                             const int* __restrict__ es, const int* __restrict__ ed,
                             const float* __restrict__ rdeg,
                             float* __restrict__ acc, int E)
{
  int t = blockIdx.x*256 + threadIdx.x;
  int e = t >> 5;
  if (e >= E) return;
  int lane = t & 31;
  int s = es[e], d = ed[e];
  float r = rdeg[d];
  float4 v = *(const float4*)(feat + (size_t)s*128 + lane*4);
  float* out = acc + (size_t)d*128 + lane*4;
  atomicAdd(out+0, v.x*r);
  atomicAdd(out+1, v.y*r);
  atomicAdd(out+2, v.z*r);
  atomicAdd(out+3, v.w*r);
}

__global__ __launch_bounds__(256) void out_head(const float* __restrict__ A,
    const float* __restrict__ W, const float* __restrict__ b,
    float* __restrict__ O, int n)
{
  __shared__ float Wl[128*16];
  __shared__ float bl[16];
  int tid = threadIdx.x;
  for (int i = tid; i < 128*16; i += 256) Wl[i] = W[i];
  if (tid < 16) bl[tid] = b[tid];
  __syncthreads();
  int row = blockIdx.x*16 + (tid >> 4);
  int col = tid & 15;
  if (row >= n) return;
  const float* Ar = A + (size_t)row*128;
  float acc = 0.f;
  #pragma unroll 8
  for (int k4 = 0; k4 < 32; ++k4) {
    float4 a = *(const float4*)(Ar + k4*4);
    acc = fmaf(a.x, Wl[(k4*4+0)*16+col], acc);
    acc = fmaf(a.y, Wl[(k4*4+1)*16+col], acc);
    acc = fmaf(a.z, Wl[(k4*4+2)*16+col], acc);
    acc = fmaf(a.w, Wl[(k4*4+3)*16+col], acc);
  }
  O[(size_t)row*16+col] = acc + bl[col];
}

extern "C" void kernel_launch(void* const* d_in, const int* in_sizes, int n_in,
                              void* d_out, int out_size, void* d_ws, size_t ws_size,
                              hipStream_t stream)
{
  const float* x_p = (const float*)d_in[0];
  const float* x_a = (const float*)d_in[1];
  const float* x_s = (const float*)d_in[2];
  const int* pa_src=(const int*)d_in[3]; const int* pa_dst=(const int*)d_in[4];
  const int* ap_src=(const int*)d_in[5]; const int* ap_dst=(const int*)d_in[6];
  const int* ps_src=(const int*)d_in[7]; const int* ps_dst=(const int*)d_in[8];
  const int* sp_src=(const int*)d_in[9]; const int* sp_dst=(const int*)d_in[10];
  const float* ewp=(const float*)d_in[11]; const float* ebp=(const float*)d_in[12];
  const float* ewa=(const float*)d_in[13]; const float* eba=(const float*)d_in[14];
  const float* ews=(const float*)d_in[15]; const float* ebs=(const float*)d_in[16];
  const float* w_pa[2]={(const float*)d_in[17],(const float*)d_in[21]};
  const float* w_ap[2]={(const float*)d_in[18],(const float*)d_in[22]};
  const float* w_ps[2]={(const float*)d_in[19],(const float*)d_in[23]};
  const float* w_sp[2]={(const float*)d_in[20],(const float*)d_in[24]};
  const float* out_w=(const float*)d_in[25]; const float* out_b=(const float*)d_in[26];
  float* out = (float*)d_out;

  float* ws = (float*)d_ws;
  float* hp  = ws;                       // NP*128
  float* ha  = hp  + (size_t)NP*128;     // NA*128
  float* hs  = ha  + (size_t)NA*128;     // NS*128
  float* ga  = hs  + (size_t)NS*128;     // NA*128  (agg of h_p over pa)
  float* gs  = ga  + (size_t)NA*128;     // NS*128  (agg of h_p over ps)  [contiguous with ga]
  float* ma  = gs  + (size_t)NS*128;     // NA*128  (h_a @ w_ap)
  float* ms  = ma  + (size_t)NA*128;     // NS*128  (h_s @ w_sp)
  float* npb = ms  + (size_t)NS*128;     // NP*128  (new paper accumulator)
  float* r_pa = npb + (size_t)NP*128;    // NA
  float* r_ps = r_pa + NA;               // NS
  float* r_ap = r_ps + NS;               // NP
  float* r_sp = r_ap + NP;               // NP   [r_* contiguous]

  // ---- degrees -> reciprocal means (constant across both layers) ----
  hipMemsetAsync(r_pa, 0, (size_t)(NA+NS+NP+NP)*sizeof(float), stream);
  deg_count<<<(EPA+255)/256,256,0,stream>>>(pa_dst, EPA, r_pa);
  deg_count<<<(EPS+255)/256,256,0,stream>>>(ps_dst, EPS, r_ps);
  deg_count<<<(EAP+255)/256,256,0,stream>>>(ap_dst, EAP, r_ap);
  deg_count<<<(ESP+255)/256,256,0,stream>>>(sp_dst, ESP, r_sp);
  recip_k<<<(NA+255)/256,256,0,stream>>>(r_pa, NA);
  recip_k<<<(NS+255)/256,256,0,stream>>>(r_ps, NS);
  recip_k<<<(NP+255)/256,256,0,stream>>>(r_ap, NP);
  recip_k<<<(NP+255)/256,256,0,stream>>>(r_sp, NP);

  // ---- encoders: h = gelu(x @ W + b), K=256 done as two K=128 chunks ----
  auto enc = [&](const float* x, const float* w, const float* b, float* h, int n){
    gemm128<<<(n+63)/64,256,0,stream>>>(x,     256, w,         h, n, nullptr, 0);
    gemm128<<<(n+63)/64,256,0,stream>>>(x+128, 256, w+128*128, h, n, b,       1|2);
  };
  enc(x_p, ewp, ebp, hp, NP);
  enc(x_a, ewa, eba, ha, NA);
  enc(x_s, ews, ebs, hs, NS);

  // ---- 2 conv layers ----
  float* pin = hp; float* pout = npb;
  for (int l = 0; l < 2; ++l) {
    // aggregate-then-transform for pa (->author) and ps (->subject)
    hipMemsetAsync(ga, 0, (size_t)(NA+NS)*128*sizeof(float), stream);  // ga+gs contiguous
    scatter_mean<<<EPA/8,256,0,stream>>>(pin, pa_src, pa_dst, r_pa, ga, EPA);
    scatter_mean<<<EPS/8,256,0,stream>>>(pin, ps_src, ps_dst, r_ps, gs, EPS);
    // transform-then-scatter for ap (author->paper) and sp (subject->paper)
    gemm128<<<(NA+63)/64,256,0,stream>>>(ha, 128, w_ap[l], ma, NA, nullptr, 0);
    gemm128<<<(NS+63)/64,256,0,stream>>>(hs, 128, w_sp[l], ms, NS, nullptr, 0);
    hipMemsetAsync(pout, 0, (size_t)NP*128*sizeof(float), stream);
    scatter_mean<<<EAP/8,256,0,stream>>>(ma, ap_src, ap_dst, r_ap, pout, EAP);
    scatter_mean<<<ESP/8,256,0,stream>>>(ms, sp_src, sp_dst, r_sp, pout, ESP);
    // finish author/subject transforms (overwrite ha/hs, no longer needed)
    gemm128<<<(NA+63)/64,256,0,stream>>>(ga, 128, w_pa[l], ha, NA, nullptr, 0);
    gemm128<<<(NS+63)/64,256,0,stream>>>(gs, 128, w_ps[l], hs, NS, nullptr, 0);
    float* t = pin; pin = pout; pout = t;
  }

  // ---- output head: final h_p @ out_w + out_b ----
  out_head<<<(NP+15)/16,256,0,stream>>>(pin, out_w, out_b, out, NP);
}

// Round 2
// 992.221 us; speedup vs baseline: 6.0665x; 6.0665x over previous
//
#include <hip/hip_runtime.h>
#include <math.h>

constexpr int NP = 100000, NA = 50000, NS = 5000;
constexpr int EPA = 600000, EAP = 600000, EPS = 200000, ESP = 200000;

__device__ __forceinline__ float gelu_f(float x) {
  float x3 = x*x*x;
  return 0.5f*x*(1.0f + tanhf(0.7978845608028654f*(x + 0.044715f*x3)));
}

// ---------------- GEMM (unchanged from R1) ----------------
// C[n,128] = A[n, (chunk of lda)] @ W[128,128]; flags: 1=accumulate into C, 2=bias+gelu epilogue
__global__ __launch_bounds__(256) void gemm128(
    const float* __restrict__ A, int lda,
    const float* __restrict__ W,
    float* __restrict__ C, int n,
    const float* __restrict__ bias, int flags)
{
  __shared__ float At[128][64];
  __shared__ float Wl[64*128];
  const int tid = threadIdx.x;

  {
    const int row = tid & 63, kq = tid >> 6;
    const int grow = blockIdx.x*64 + row;
    const float* Ar = A + (size_t)grow * lda;
    #pragma unroll
    for (int i = 0; i < 8; ++i) {
      const int k0 = kq*32 + i*4;
      float4 v = make_float4(0.f,0.f,0.f,0.f);
      if (grow < n) v = *(const float4*)(Ar + k0);
      At[k0+0][row] = v.x; At[k0+1][row] = v.y;
      At[k0+2][row] = v.z; At[k0+3][row] = v.w;
    }
  }

  const int rg = tid >> 4;
  const int cg = tid & 15;
  float acc[4][8];
  #pragma unroll
  for (int i=0;i<4;++i)
    #pragma unroll
    for (int j=0;j<8;++j) acc[i][j]=0.f;

  for (int kc = 0; kc < 2; ++kc) {
    __syncthreads();
    {
      const float4* W4 = (const float4*)(W + kc*64*128);
      float4* Wl4 = (float4*)Wl;
      #pragma unroll
      for (int i = 0; i < 8; ++i) Wl4[tid + i*256] = W4[tid + i*256];
    }
    __syncthreads();
    #pragma unroll 4
    for (int k = 0; k < 64; ++k) {
      const float4 a   = *(const float4*)&At[kc*64 + k][rg*4];
      const float4 wlo = *(const float4*)&Wl[k*128 + cg*4];
      const float4 whi = *(const float4*)&Wl[k*128 + 64 + cg*4];
      const float av[4] = {a.x,a.y,a.z,a.w};
      const float wl_[4] = {wlo.x,wlo.y,wlo.z,wlo.w};
      const float wh_[4] = {whi.x,whi.y,whi.z,whi.w};
      #pragma unroll
      for (int i=0;i<4;++i) {
        #pragma unroll
        for (int j=0;j<4;++j) {
          acc[i][j]   = fmaf(av[i], wl_[j], acc[i][j]);
          acc[i][j+4] = fmaf(av[i], wh_[j], acc[i][j+4]);
        }
      }
    }
  }

  const int rbase = blockIdx.x*64 + rg*4;
  #pragma unroll
  for (int i=0;i<4;++i) {
    const int r = rbase + i;
    if (r >= n) break;
    float* Cr = C + (size_t)r*128;
    #pragma unroll
    for (int h=0; h<2; ++h) {
      const int c0 = h*64 + cg*4;
      float4 v = make_float4(acc[i][h*4+0], acc[i][h*4+1], acc[i][h*4+2], acc[i][h*4+3]);
      if (flags & 1) {
        float4 old = *(const float4*)(Cr + c0);
        v.x+=old.x; v.y+=old.y; v.z+=old.z; v.w+=old.w;
      }
      if (flags & 2) {
        v.x = gelu_f(v.x + bias[c0+0]);
        v.y = gelu_f(v.y + bias[c0+1]);
        v.z = gelu_f(v.z + bias[c0+2]);
        v.w = gelu_f(v.w + bias[c0+3]);
      }
      *(float4*)(Cr + c0) = v;
    }
  }
}

// ---------------- CSR construction ----------------
__global__ void deg_count_i(const int* __restrict__ dst, int E, int* __restrict__ deg) {
  int e = blockIdx.x*256 + threadIdx.x;
  if (e < E) atomicAdd(&deg[dst[e]], 1);
}

// per-block (4096-chunk) sum
__global__ __launch_bounds__(256) void scan_partial(const int* __restrict__ in, int n,
                                                    int* __restrict__ part) {
  __shared__ int red[4];
  int base = blockIdx.x*4096;
  int sum = 0;
  for (int i = threadIdx.x; i < 4096; i += 256) {
    int idx = base + i;
    sum += (idx < n) ? in[idx] : 0;
  }
  #pragma unroll
  for (int off = 32; off; off >>= 1) sum += __shfl_down(sum, off, 64);
  if ((threadIdx.x & 63) == 0) red[threadIdx.x >> 6] = sum;
  __syncthreads();
  if (threadIdx.x == 0) part[blockIdx.x] = red[0]+red[1]+red[2]+red[3];
}

// exclusive scan within chunk + chunk offset; writes out[0..n] (n+1 entries)
__global__ __launch_bounds__(256) void scan_chunk(const int* __restrict__ in, int n,
    const int* __restrict__ part, int* __restrict__ out)
{
  int off0 = 0;
  for (int i = 0; i < (int)blockIdx.x; ++i) off0 += part[i];
  const int base = blockIdx.x*4096 + threadIdx.x*16;
  int loc[16]; int s = 0;
  #pragma unroll
  for (int j = 0; j < 16; ++j) {
    int idx = base + j;
    int v = (idx < n) ? in[idx] : 0;
    loc[j] = s; s += v;
  }
  __shared__ int ts[256];
  ts[threadIdx.x] = s; __syncthreads();
  for (int off = 1; off < 256; off <<= 1) {
    int t = (threadIdx.x >= off) ? ts[threadIdx.x - off] : 0;
    __syncthreads();
    ts[threadIdx.x] += t;
    __syncthreads();
  }
  int excl = off0 + ts[threadIdx.x] - s;
  #pragma unroll
  for (int j = 0; j < 16; ++j) {
    int idx = base + j;
    if (idx < n) out[idx] = excl + loc[j];
    if (idx == n-1) out[n] = excl + loc[j] + in[idx];
  }
}

__global__ void csr_fill(const int* __restrict__ src, const int* __restrict__ dst, int E,
    const int* __restrict__ rp, int* __restrict__ cur, int* __restrict__ ci)
{
  int e = blockIdx.x*256 + threadIdx.x;
  if (e < E) {
    int d = dst[e];
    int p = atomicAdd(&cur[d], 1);
    ci[rp[d] + p] = src[e];
  }
}

// ---------------- gather-mean aggregation (no atomics) ----------------
__device__ __forceinline__ void f4acc(float4& a, const float4 v) {
  a.x += v.x; a.y += v.y; a.z += v.z; a.w += v.w;
}

__device__ __forceinline__ float4 gather_row(const float* __restrict__ f,
    const int* __restrict__ ci, int beg, int end, int lane)
{
  float4 a0 = make_float4(0.f,0.f,0.f,0.f), a1 = make_float4(0.f,0.f,0.f,0.f);
  int e = beg;
  for (; e + 1 < end; e += 2) {
    int s0 = ci[e], s1 = ci[e+1];
    f4acc(a0, *(const float4*)(f + (size_t)s0*128 + lane*4));
    f4acc(a1, *(const float4*)(f + (size_t)s1*128 + lane*4));
  }
  if (e < end) {
    int s0 = ci[e];
    f4acc(a0, *(const float4*)(f + (size_t)s0*128 + lane*4));
  }
  int d = end - beg;
  float r = 1.0f / (float)(d > 0 ? d : 1);
  return make_float4((a0.x+a1.x)*r, (a0.y+a1.y)*r, (a0.z+a1.z)*r, (a0.w+a1.w)*r);
}

// out[row] = mean_{e in csr(row)} feat[src_e]
__global__ __launch_bounds__(256) void gather_mean(const float* __restrict__ feat,
    const int* __restrict__ rp, const int* __restrict__ ci,
    float* __restrict__ out, int n)
{
  int t = blockIdx.x*256 + threadIdx.x;
  int row = t >> 5, lane = t & 31;
  if (row >= n) return;
  float4 res = gather_row(feat, ci, rp[row], rp[row+1], lane);
  *(float4*)(out + (size_t)row*128 + lane*4) = res;
}

// out[row] = mean over rel1 of f1 + mean over rel2 of f2
__global__ __launch_bounds__(256) void gather2_mean_sum(
    const float* __restrict__ f1, const int* __restrict__ rp1, const int* __restrict__ ci1,
    const float* __restrict__ f2, const int* __restrict__ rp2, const int* __restrict__ ci2,
    float* __restrict__ out, int n)
{
  int t = blockIdx.x*256 + threadIdx.x;
  int row = t >> 5, lane = t & 31;
  if (row >= n) return;
  float4 r1 = gather_row(f1, ci1, rp1[row], rp1[row+1], lane);
  float4 r2 = gather_row(f2, ci2, rp2[row], rp2[row+1], lane);
  *(float4*)(out + (size_t)row*128 + lane*4) =
      make_float4(r1.x+r2.x, r1.y+r2.y, r1.z+r2.z, r1.w+r2.w);
}

// ---------------- output head ----------------
__global__ __launch_bounds__(256) void out_head(const float* __restrict__ A,
    const float* __restrict__ W, const float* __restrict__ b,
    float* __restrict__ O, int n)
{
  __shared__ float Wl[128*16];
  __shared__ float bl[16];
  int tid = threadIdx.x;
  for (int i = tid; i < 128*16; i += 256) Wl[i] = W[i];
  if (tid < 16) bl[tid] = b[tid];
  __syncthreads();
  int row = blockIdx.x*16 + (tid >> 4);
  int col = tid & 15;
  if (row >= n) return;
  const float* Ar = A + (size_t)row*128;
  float acc = 0.f;
  #pragma unroll 8
  for (int k4 = 0; k4 < 32; ++k4) {
    float4 a = *(const float4*)(Ar + k4*4);
    acc = fmaf(a.x, Wl[(k4*4+0)*16+col], acc);
    acc = fmaf(a.y, Wl[(k4*4+1)*16+col], acc);
    acc = fmaf(a.z, Wl[(k4*4+2)*16+col], acc);
    acc = fmaf(a.w, Wl[(k4*4+3)*16+col], acc);
  }
  O[(size_t)row*16+col] = acc + bl[col];
}

extern "C" void kernel_launch(void* const* d_in, const int* in_sizes, int n_in,
                              void* d_out, int out_size, void* d_ws, size_t ws_size,
                              hipStream_t stream)
{
  const float* x_p = (const float*)d_in[0];
  const float* x_a = (const float*)d_in[1];
  const float* x_s = (const float*)d_in[2];
  const int* pa_src=(const int*)d_in[3]; const int* pa_dst=(const int*)d_in[4];
  const int* ap_src=(const int*)d_in[5]; const int* ap_dst=(const int*)d_in[6];
  const int* ps_src=(const int*)d_in[7]; const int* ps_dst=(const int*)d_in[8];
  const int* sp_src=(const int*)d_in[9]; const int* sp_dst=(const int*)d_in[10];
  const float* ewp=(const float*)d_in[11]; const float* ebp=(const float*)d_in[12];
  const float* ewa=(const float*)d_in[13]; const float* eba=(const float*)d_in[14];
  const float* ews=(const float*)d_in[15]; const float* ebs=(const float*)d_in[16];
  const float* w_pa[2]={(const float*)d_in[17],(const float*)d_in[21]};
  const float* w_ap[2]={(const float*)d_in[18],(const float*)d_in[22]};
  const float* w_ps[2]={(const float*)d_in[19],(const float*)d_in[23]};
  const float* w_sp[2]={(const float*)d_in[20],(const float*)d_in[24]};
  const float* out_w=(const float*)d_in[25]; const float* out_b=(const float*)d_in[26];
  float* out = (float*)d_out;

  // ---- workspace layout ----
  float* ws = (float*)d_ws;
  float* hp  = ws;
  float* ha  = hp  + (size_t)NP*128;
  float* hs  = ha  + (size_t)NA*128;
  float* ga  = hs  + (size_t)NS*128;
  float* gs  = ga  + (size_t)NA*128;
  float* ma  = gs  + (size_t)NS*128;
  float* ms  = ma  + (size_t)NA*128;
  float* npb = ms  + (size_t)NS*128;
  int* deg_pa = (int*)(npb + (size_t)NP*128);  // NA
  int* deg_ps = deg_pa + NA;                   // NS
  int* deg_ap = deg_ps + NS;                   // NP
  int* deg_sp = deg_ap + NP;                   // NP
  int* rp_pa  = deg_sp + NP;                   // NA+1
  int* rp_ps  = rp_pa + NA + 1;                // NS+1
  int* rp_ap  = rp_ps + NS + 1;                // NP+1
  int* rp_sp  = rp_ap + NP + 1;                // NP+1
  int* cursor = rp_sp + NP + 1;                // NP
  int* part   = cursor + NP;                   // 64
  int* ws_end = part + 64;

  const size_t csr_ints = (size_t)EPA + EPS + EAP + ESP;  // 1.6M
  size_t base_bytes = (size_t)((char*)ws_end - (char*)d_ws);
  int* csr_base;
  if (ws_size >= base_bytes + csr_ints*sizeof(int))
    csr_base = ws_end;                 // fits in workspace
  else
    csr_base = (int*)d_out;            // use d_out as scratch; overwritten by out_head last
  int* csr_pa = csr_base;
  int* csr_ps = csr_pa + EPA;
  int* csr_ap = csr_ps + EPS;
  int* csr_sp = csr_ap + EAP;

  // ---- build CSR for all 4 relations ----
  hipMemsetAsync(deg_pa, 0, (size_t)(NA+NS+NP+NP)*sizeof(int), stream);
  deg_count_i<<<(EPA+255)/256,256,0,stream>>>(pa_dst, EPA, deg_pa);
  deg_count_i<<<(EPS+255)/256,256,0,stream>>>(ps_dst, EPS, deg_ps);
  deg_count_i<<<(EAP+255)/256,256,0,stream>>>(ap_dst, EAP, deg_ap);
  deg_count_i<<<(ESP+255)/256,256,0,stream>>>(sp_dst, ESP, deg_sp);

  struct Rel { const int* src; const int* dst; int E; int n; int* deg; int* rp; int* ci; };
  Rel rels[4] = {
    {pa_src, pa_dst, EPA, NA, deg_pa, rp_pa, csr_pa},
    {ps_src, ps_dst, EPS, NS, deg_ps, rp_ps, csr_ps},
    {ap_src, ap_dst, EAP, NP, deg_ap, rp_ap, csr_ap},
    {sp_src, sp_dst, ESP, NP, deg_sp, rp_sp, csr_sp},
  };
  for (int i = 0; i < 4; ++i) {
    Rel& r = rels[i];
    int nch = (r.n + 4095)/4096;
    scan_partial<<<nch,256,0,stream>>>(r.deg, r.n, part);
    scan_chunk  <<<nch,256,0,stream>>>(r.deg, r.n, part, r.rp);
    hipMemsetAsync(cursor, 0, (size_t)r.n*sizeof(int), stream);
    csr_fill<<<(r.E+255)/256,256,0,stream>>>(r.src, r.dst, r.E, r.rp, cursor, r.ci);
  }

  // ---- encoders: h = gelu(x @ W + b), K=256 as two K=128 chunks ----
  auto enc = [&](const float* x, const float* w, const float* b, float* h, int n){
    gemm128<<<(n+63)/64,256,0,stream>>>(x,     256, w,         h, n, nullptr, 0);
    gemm128<<<(n+63)/64,256,0,stream>>>(x+128, 256, w+128*128, h, n, b,       1|2);
  };
  enc(x_p, ewp, ebp, hp, NP);
  enc(x_a, ewa, eba, ha, NA);
  enc(x_s, ews, ebs, hs, NS);

  // ---- 2 conv layers ----
  float* pin = hp; float* pout = npb;
  for (int l = 0; l < 2; ++l) {
    // aggregate-then-transform toward author/subject
    gather_mean<<<(NA+7)/8,256,0,stream>>>(pin, rp_pa, csr_pa, ga, NA);
    gather_mean<<<(NS+7)/8,256,0,stream>>>(pin, rp_ps, csr_ps, gs, NS);
    // transform-then-aggregate toward paper
    gemm128<<<(NA+63)/64,256,0,stream>>>(ha, 128, w_ap[l], ma, NA, nullptr, 0);
    gemm128<<<(NS+63)/64,256,0,stream>>>(hs, 128, w_sp[l], ms, NS, nullptr, 0);
    gather2_mean_sum<<<(NP+7)/8,256,0,stream>>>(ma, rp_ap, csr_ap,
                                                ms, rp_sp, csr_sp, pout, NP);
    // finish author/subject transforms (overwrite ha/hs)
    gemm128<<<(NA+63)/64,256,0,stream>>>(ga, 128, w_pa[l], ha, NA, nullptr, 0);
    gemm128<<<(NS+63)/64,256,0,stream>>>(gs, 128, w_ps[l], hs, NS, nullptr, 0);
    float* t = pin; pin = pout; pout = t;
  }

  // ---- output head ----
  out_head<<<(NP+15)/16,256,0,stream>>>(pin, out_w, out_b, out, NP);
}

// Round 3
// 643.793 us; speedup vs baseline: 9.3498x; 1.5412x over previous
//
#include <hip/hip_runtime.h>
#include <math.h>

constexpr int NP = 100000, NA = 50000, NS = 5000;
constexpr int EPA = 600000, EAP = 600000, EPS = 200000, ESP = 200000;

typedef short s16x8 __attribute__((ext_vector_type(8)));
typedef float f32x4 __attribute__((ext_vector_type(4)));
typedef unsigned short u16;

__device__ __forceinline__ float gelu_f(float x) {
  float x3 = x*x*x;
  return 0.5f*x*(1.0f + tanhf(0.7978845608028654f*(x + 0.044715f*x3)));
}
__device__ __forceinline__ u16 f2bf(float f) {
  unsigned u = __float_as_uint(f);
  u += 0x7fffu + ((u >> 16) & 1u);     // RNE
  return (u16)(u >> 16);
}
__device__ __forceinline__ float bf2f(u16 s) {
  return __uint_as_float((unsigned)s << 16);
}

// ---------------- W fragment packing ----------------
// Wp[((ks*8+cf)*64 + l)*8 + b] = bf16( W[ks*32 + (l>>4)*8 + b][cf*16 + (l&15)] )
__global__ void pack_w(const float* __restrict__ W, u16* __restrict__ Wp, int K) {
  int o = blockIdx.x*256 + threadIdx.x;
  if (o >= K*128) return;
  int b  = o & 7;
  int l  = (o >> 3) & 63;
  int cf = (o >> 9) & 7;
  int ks = o >> 12;
  int k   = ks*32 + (l >> 4)*8 + b;
  int col = cf*16 + (l & 15);
  Wp[o] = f2bf(W[k*128 + col]);
}

// ---------------- MFMA GEMM: C[n,128] = A[n,K] @ W[K,128] ----------------
// block = 256 thr = 4 waves; wave covers 32 rows x 128 cols; no LDS.
template<int K, bool AF32, bool GELU_>
__global__ __launch_bounds__(256) void mfma_gemm(
    const void* __restrict__ Av, const u16* __restrict__ Wp,
    const float* __restrict__ bias, u16* __restrict__ C, int n)
{
  const int lane = threadIdx.x & 63;
  const int wv   = threadIdx.x >> 6;
  const int rowbase = blockIdx.x*128 + wv*32;
  const int m  = lane & 15;
  const int kq = lane >> 4;

  f32x4 acc[2][8];
  #pragma unroll
  for (int i = 0; i < 2; ++i)
    #pragma unroll
    for (int j = 0; j < 8; ++j) acc[i][j] = (f32x4){0.f,0.f,0.f,0.f};

  const int r0 = rowbase + m, r1 = rowbase + 16 + m;
  const bool v0 = r0 < n, v1 = r1 < n;

  #pragma unroll
  for (int ks = 0; ks < K/32; ++ks) {
    s16x8 a0 = {0,0,0,0,0,0,0,0}, a1 = {0,0,0,0,0,0,0,0};
    if (AF32) {
      const float* A0 = (const float*)Av + (size_t)r0*K + ks*32 + kq*8;
      const float* A1 = (const float*)Av + (size_t)r1*K + ks*32 + kq*8;
      if (v0) {
        float4 f = *(const float4*)A0, g = *(const float4*)(A0+4);
        a0[0]=(short)f2bf(f.x); a0[1]=(short)f2bf(f.y); a0[2]=(short)f2bf(f.z); a0[3]=(short)f2bf(f.w);
        a0[4]=(short)f2bf(g.x); a0[5]=(short)f2bf(g.y); a0[6]=(short)f2bf(g.z); a0[7]=(short)f2bf(g.w);
      }
      if (v1) {
        float4 f = *(const float4*)A1, g = *(const float4*)(A1+4);
        a1[0]=(short)f2bf(f.x); a1[1]=(short)f2bf(f.y); a1[2]=(short)f2bf(f.z); a1[3]=(short)f2bf(f.w);
        a1[4]=(short)f2bf(g.x); a1[5]=(short)f2bf(g.y); a1[6]=(short)f2bf(g.z); a1[7]=(short)f2bf(g.w);
      }
    } else {
      if (v0) a0 = *(const s16x8*)((const u16*)Av + (size_t)r0*K + ks*32 + kq*8);
      if (v1) a1 = *(const s16x8*)((const u16*)Av + (size_t)r1*K + ks*32 + kq*8);
    }
    const s16x8* Wf = (const s16x8*)Wp + (size_t)ks*512 + lane;
    #pragma unroll
    for (int cf = 0; cf < 8; ++cf) {
      s16x8 b = Wf[cf*64];
      acc[0][cf] = __builtin_amdgcn_mfma_f32_16x16x32_bf16(a0, b, acc[0][cf], 0, 0, 0);
      acc[1][cf] = __builtin_amdgcn_mfma_f32_16x16x32_bf16(a1, b, acc[1][cf], 0, 0, 0);
    }
  }

  // D layout: col = lane&15, row = (lane>>4)*4 + reg   [m89-verified]
  #pragma unroll
  for (int rg = 0; rg < 2; ++rg) {
    const int rb = rowbase + rg*16 + kq*4;
    #pragma unroll
    for (int cf = 0; cf < 8; ++cf) {
      const int col = cf*16 + m;
      #pragma unroll
      for (int r = 0; r < 4; ++r) {
        const int row = rb + r;
        if (row < n) {
          float v = acc[rg][cf][r];
          if (GELU_) v = gelu_f(v + bias[col]);
          C[(size_t)row*128 + col] = f2bf(v);
        }
      }
    }
  }
}

// ---------------- CSR construction ----------------
__global__ void deg_count_i(const int* __restrict__ dst, int E, int* __restrict__ deg) {
  int e = blockIdx.x*256 + threadIdx.x;
  if (e < E) atomicAdd(&deg[dst[e]], 1);
}

__global__ __launch_bounds__(256) void scan_partial(const int* __restrict__ in, int n,
                                                    int* __restrict__ part) {
  __shared__ int red[4];
  int base = blockIdx.x*4096;
  int sum = 0;
  for (int i = threadIdx.x; i < 4096; i += 256) {
    int idx = base + i;
    sum += (idx < n) ? in[idx] : 0;
  }
  #pragma unroll
  for (int off = 32; off; off >>= 1) sum += __shfl_down(sum, off, 64);
  if ((threadIdx.x & 63) == 0) red[threadIdx.x >> 6] = sum;
  __syncthreads();
  if (threadIdx.x == 0) part[blockIdx.x] = red[0]+red[1]+red[2]+red[3];
}

__global__ __launch_bounds__(256) void scan_chunk(const int* __restrict__ in, int n,
    const int* __restrict__ part, int* __restrict__ out)
{
  int off0 = 0;
  for (int i = 0; i < (int)blockIdx.x; ++i) off0 += part[i];
  const int base = blockIdx.x*4096 + threadIdx.x*16;
  int loc[16]; int s = 0;
  #pragma unroll
  for (int j = 0; j < 16; ++j) {
    int idx = base + j;
    int v = (idx < n) ? in[idx] : 0;
    loc[j] = s; s += v;
  }
  __shared__ int ts[256];
  ts[threadIdx.x] = s; __syncthreads();
  for (int off = 1; off < 256; off <<= 1) {
    int t = (threadIdx.x >= off) ? ts[threadIdx.x - off] : 0;
    __syncthreads();
    ts[threadIdx.x] += t;
    __syncthreads();
  }
  int excl = off0 + ts[threadIdx.x] - s;
  #pragma unroll
  for (int j = 0; j < 16; ++j) {
    int idx = base + j;
    if (idx < n) out[idx] = excl + loc[j];
    if (idx == n-1) out[n] = excl + loc[j] + in[idx];
  }
}

__global__ void csr_fill(const int* __restrict__ src, const int* __restrict__ dst, int E,
    const int* __restrict__ rp, int* __restrict__ cur, int* __restrict__ ci)
{
  int e = blockIdx.x*256 + threadIdx.x;
  if (e < E) {
    int d = dst[e];
    int p = atomicAdd(&cur[d], 1);
    ci[rp[d] + p] = src[e];
  }
}

// ---------------- gather-mean aggregation (bf16 features, f32 accum) ----------------
__device__ __forceinline__ void acc4(float* a, uint2 v) {
  a[0] += bf2f((u16)(v.x & 0xffff)); a[1] += bf2f((u16)(v.x >> 16));
  a[2] += bf2f((u16)(v.y & 0xffff)); a[3] += bf2f((u16)(v.y >> 16));
}

__device__ __forceinline__ void gather_row_bf(const u16* __restrict__ f,
    const int* __restrict__ ci, int beg, int end, int lane, float* a)
{
  float b[4] = {0.f,0.f,0.f,0.f};
  int e = beg;
  for (; e + 1 < end; e += 2) {
    int s0 = ci[e], s1 = ci[e+1];
    uint2 u0 = *(const uint2*)(f + (size_t)s0*128 + lane*4);
    uint2 u1 = *(const uint2*)(f + (size_t)s1*128 + lane*4);
    acc4(a, u0); acc4(b, u1);
  }
  if (e < end) {
    uint2 u0 = *(const uint2*)(f + (size_t)ci[e]*128 + lane*4);
    acc4(a, u0);
  }
  int d = end - beg;
  float r = 1.0f / (float)(d > 0 ? d : 1);
  #pragma unroll
  for (int i = 0; i < 4; ++i) a[i] = (a[i] + b[i]) * r;
}

__device__ __forceinline__ uint2 pack4(const float* a) {
  uint2 o;
  o.x = (unsigned)f2bf(a[0]) | ((unsigned)f2bf(a[1]) << 16);
  o.y = (unsigned)f2bf(a[2]) | ((unsigned)f2bf(a[3]) << 16);
  return o;
}

__global__ __launch_bounds__(256) void gather_mean(const u16* __restrict__ feat,
    const int* __restrict__ rp, const int* __restrict__ ci,
    u16* __restrict__ out, int n)
{
  int t = blockIdx.x*256 + threadIdx.x;
  int row = t >> 5, lane = t & 31;
  if (row >= n) return;
  float a[4] = {0.f,0.f,0.f,0.f};
  gather_row_bf(feat, ci, rp[row], rp[row+1], lane, a);
  *(uint2*)(out + (size_t)row*128 + lane*4) = pack4(a);
}

__global__ __launch_bounds__(256) void gather2_mean_sum(
    const u16* __restrict__ f1, const int* __restrict__ rp1, const int* __restrict__ ci1,
    const u16* __restrict__ f2, const int* __restrict__ rp2, const int* __restrict__ ci2,
    u16* __restrict__ out, int n)
{
  int t = blockIdx.x*256 + threadIdx.x;
  int row = t >> 5, lane = t & 31;
  if (row >= n) return;
  float a[4] = {0.f,0.f,0.f,0.f};
  float c[4] = {0.f,0.f,0.f,0.f};
  gather_row_bf(f1, ci1, rp1[row], rp1[row+1], lane, a);
  gather_row_bf(f2, ci2, rp2[row], rp2[row+1], lane, c);
  #pragma unroll
  for (int i = 0; i < 4; ++i) a[i] += c[i];
  *(uint2*)(out + (size_t)row*128 + lane*4) = pack4(a);
}

// ---------------- output head (bf16 in, f32 math, f32 out) ----------------
__global__ __launch_bounds__(256) void out_head(const u16* __restrict__ A,
    const float* __restrict__ W, const float* __restrict__ b,
    float* __restrict__ O, int n)
{
  __shared__ float Wl[128*16];
  __shared__ float bl[16];
  int tid = threadIdx.x;
  for (int i = tid; i < 128*16; i += 256) Wl[i] = W[i];
  if (tid < 16) bl[tid] = b[tid];
  __syncthreads();
  int row = blockIdx.x*16 + (tid >> 4);
  int col = tid & 15;
  if (row >= n) return;
  const u16* Ar = A + (size_t)row*128;
  float acc = 0.f;
  #pragma unroll 8
  for (int k4 = 0; k4 < 32; ++k4) {
    uint2 v = *(const uint2*)(Ar + k4*4);
    acc = fmaf(bf2f((u16)(v.x & 0xffff)), Wl[(k4*4+0)*16+col], acc);
    acc = fmaf(bf2f((u16)(v.x >> 16)),    Wl[(k4*4+1)*16+col], acc);
    acc = fmaf(bf2f((u16)(v.y & 0xffff)), Wl[(k4*4+2)*16+col], acc);
    acc = fmaf(bf2f((u16)(v.y >> 16)),    Wl[(k4*4+3)*16+col], acc);
  }
  O[(size_t)row*16+col] = acc + bl[col];
}

extern "C" void kernel_launch(void* const* d_in, const int* in_sizes, int n_in,
                              void* d_out, int out_size, void* d_ws, size_t ws_size,
                              hipStream_t stream)
{
  const float* x_p = (const float*)d_in[0];
  const float* x_a = (const float*)d_in[1];
  const float* x_s = (const float*)d_in[2];
  const int* pa_src=(const int*)d_in[3]; const int* pa_dst=(const int*)d_in[4];
  const int* ap_src=(const int*)d_in[5]; const int* ap_dst=(const int*)d_in[6];
  const int* ps_src=(const int*)d_in[7]; const int* ps_dst=(const int*)d_in[8];
  const int* sp_src=(const int*)d_in[9]; const int* sp_dst=(const int*)d_in[10];
  const float* ewp=(const float*)d_in[11]; const float* ebp=(const float*)d_in[12];
  const float* ewa=(const float*)d_in[13]; const float* eba=(const float*)d_in[14];
  const float* ews=(const float*)d_in[15]; const float* ebs=(const float*)d_in[16];
  const float* w_ap[2]={(const float*)d_in[18],(const float*)d_in[22]};
  const float* w_pa[2]={(const float*)d_in[17],(const float*)d_in[21]};
  const float* w_ps[2]={(const float*)d_in[19],(const float*)d_in[23]};
  const float* w_sp[2]={(const float*)d_in[20],(const float*)d_in[24]};
  const float* out_w=(const float*)d_in[25]; const float* out_b=(const float*)d_in[26];
  float* out = (float*)d_out;

  // ---- workspace layout (256B-aligned chunks) ----
  char* wp = (char*)d_ws;
  auto alloc = [&](size_t bytes) { char* p = wp; wp += (bytes + 255) & ~(size_t)255; return p; };
  u16* hp  = (u16*)alloc((size_t)NP*128*2);
  u16* ha  = (u16*)alloc((size_t)NA*128*2);
  u16* hs  = (u16*)alloc((size_t)NS*128*2);
  u16* ga  = (u16*)alloc((size_t)NA*128*2);
  u16* gs  = (u16*)alloc((size_t)NS*128*2);
  u16* ma  = (u16*)alloc((size_t)NA*128*2);
  u16* ms  = (u16*)alloc((size_t)NS*128*2);
  u16* npb = (u16*)alloc((size_t)NP*128*2);
  u16* wpk_p = (u16*)alloc((size_t)256*128*2);   // packed encoder weights
  u16* wpk_a = (u16*)alloc((size_t)256*128*2);
  u16* wpk_s = (u16*)alloc((size_t)256*128*2);
  u16* wpk_c[8];                                  // conv weights: [l*4 + {ap,sp,pa,ps}]
  for (int i = 0; i < 8; ++i) wpk_c[i] = (u16*)alloc((size_t)128*128*2);
  int* deg_pa = (int*)alloc((size_t)NA*4);
  int* deg_ps = (int*)alloc((size_t)NS*4);
  int* deg_ap = (int*)alloc((size_t)NP*4);
  int* deg_sp = (int*)alloc((size_t)NP*4);
  int* rp_pa  = (int*)alloc((size_t)(NA+1)*4);
  int* rp_ps  = (int*)alloc((size_t)(NS+1)*4);
  int* rp_ap  = (int*)alloc((size_t)(NP+1)*4);
  int* rp_sp  = (int*)alloc((size_t)(NP+1)*4);
  int* cursor = (int*)alloc((size_t)NP*4);
  int* part   = (int*)alloc((size_t)64*4);

  const size_t csr_ints = (size_t)EPA + EPS + EAP + ESP;  // 1.6M == out_size
  int* csr_base;
  size_t used = (size_t)(wp - (char*)d_ws);
  if (ws_size >= used + csr_ints*sizeof(int))
    csr_base = (int*)alloc(csr_ints*sizeof(int));
  else
    csr_base = (int*)d_out;   // scratch; fully overwritten by out_head at the end
  int* csr_pa = csr_base;
  int* csr_ps = csr_pa + EPA;
  int* csr_ap = csr_ps + EPS;
  int* csr_sp = csr_ap + EAP;

  // ---- pack weights into fragment order ----
  pack_w<<<(256*128+255)/256,256,0,stream>>>(ewp, wpk_p, 256);
  pack_w<<<(256*128+255)/256,256,0,stream>>>(ewa, wpk_a, 256);
  pack_w<<<(256*128+255)/256,256,0,stream>>>(ews, wpk_s, 256);
  for (int l = 0; l < 2; ++l) {
    pack_w<<<(128*128+255)/256,256,0,stream>>>(w_ap[l], wpk_c[l*4+0], 128);
    pack_w<<<(128*128+255)/256,256,0,stream>>>(w_sp[l], wpk_c[l*4+1], 128);
    pack_w<<<(128*128+255)/256,256,0,stream>>>(w_pa[l], wpk_c[l*4+2], 128);
    pack_w<<<(128*128+255)/256,256,0,stream>>>(w_ps[l], wpk_c[l*4+3], 128);
  }

  // ---- build CSR for all 4 relations ----
  hipMemsetAsync(deg_pa, 0, (size_t)NA*4, stream);
  hipMemsetAsync(deg_ps, 0, (size_t)NS*4, stream);
  hipMemsetAsync(deg_ap, 0, (size_t)NP*4, stream);
  hipMemsetAsync(deg_sp, 0, (size_t)NP*4, stream);
  deg_count_i<<<(EPA+255)/256,256,0,stream>>>(pa_dst, EPA, deg_pa);
  deg_count_i<<<(EPS+255)/256,256,0,stream>>>(ps_dst, EPS, deg_ps);
  deg_count_i<<<(EAP+255)/256,256,0,stream>>>(ap_dst, EAP, deg_ap);
  deg_count_i<<<(ESP+255)/256,256,0,stream>>>(sp_dst, ESP, deg_sp);

  struct Rel { const int* src; const int* dst; int E; int n; int* deg; int* rp; int* ci; };
  Rel rels[4] = {
    {pa_src, pa_dst, EPA, NA, deg_pa, rp_pa, csr_pa},
    {ps_src, ps_dst, EPS, NS, deg_ps, rp_ps, csr_ps},
    {ap_src, ap_dst, EAP, NP, deg_ap, rp_ap, csr_ap},
    {sp_src, sp_dst, ESP, NP, deg_sp, rp_sp, csr_sp},
  };
  for (int i = 0; i < 4; ++i) {
    Rel& r = rels[i];
    int nch = (r.n + 4095)/4096;
    scan_partial<<<nch,256,0,stream>>>(r.deg, r.n, part);
    scan_chunk  <<<nch,256,0,stream>>>(r.deg, r.n, part, r.rp);
    hipMemsetAsync(cursor, 0, (size_t)r.n*4, stream);
    csr_fill<<<(r.E+255)/256,256,0,stream>>>(r.src, r.dst, r.E, r.rp, cursor, r.ci);
  }

  // ---- encoders: h = gelu(x @ W + b), full K=256, f32 A converted in-register ----
  mfma_gemm<256,true,true><<<(NP+127)/128,256,0,stream>>>(x_p, wpk_p, ebp, hp, NP);
  mfma_gemm<256,true,true><<<(NA+127)/128,256,0,stream>>>(x_a, wpk_a, eba, ha, NA);
  mfma_gemm<256,true,true><<<(NS+127)/128,256,0,stream>>>(x_s, wpk_s, ebs, hs, NS);

  // ---- layer 0 (full) ----
  gather_mean<<<((size_t)NA*32+255)/256,256,0,stream>>>(hp, rp_pa, csr_pa, ga, NA);
  gather_mean<<<((size_t)NS*32+255)/256,256,0,stream>>>(hp, rp_ps, csr_ps, gs, NS);
  mfma_gemm<128,false,false><<<(NA+127)/128,256,0,stream>>>(ha, wpk_c[0], nullptr, ma, NA);
  mfma_gemm<128,false,false><<<(NS+127)/128,256,0,stream>>>(hs, wpk_c[1], nullptr, ms, NS);
  gather2_mean_sum<<<((size_t)NP*32+255)/256,256,0,stream>>>(ma, rp_ap, csr_ap,
                                                             ms, rp_sp, csr_sp, npb, NP);
  mfma_gemm<128,false,false><<<(NA+127)/128,256,0,stream>>>(ga, wpk_c[2], nullptr, ha, NA);
  mfma_gemm<128,false,false><<<(NS+127)/128,256,0,stream>>>(gs, wpk_c[3], nullptr, hs, NS);

  // ---- layer 1 (only the paper path is consumed downstream) ----
  mfma_gemm<128,false,false><<<(NA+127)/128,256,0,stream>>>(ha, wpk_c[4], nullptr, ma, NA);
  mfma_gemm<128,false,false><<<(NS+127)/128,256,0,stream>>>(hs, wpk_c[5], nullptr, ms, NS);
  gather2_mean_sum<<<((size_t)NP*32+255)/256,256,0,stream>>>(ma, rp_ap, csr_ap,
                                                             ms, rp_sp, csr_sp, hp, NP);

  // ---- output head ----
  out_head<<<(NP+15)/16,256,0,stream>>>(hp, out_w, out_b, out, NP);
}

// Round 4
// 327.343 us; speedup vs baseline: 18.3884x; 1.9667x over previous
//
#include <hip/hip_runtime.h>
#include <math.h>

constexpr int NP = 100000, NA = 50000, NS = 5000;
constexpr int EPA = 600000, EAP = 600000, EPS = 200000, ESP = 200000;
// concatenated relation order: pa | ps | ap | sp   (dst spaces: A | S | P | P)
constexpr int ETOT = EPA + EPS + EAP + ESP;            // 1.6M
constexpr int NT   = NA + NS + NP + NP;                // 255000 global dst rows
constexpr int OFF_PS = EPA, OFF_AP = EPA + EPS, OFF_SP = EPA + EPS + EAP;
constexpr int ROW_PS = NA, ROW_AP = NA + NS, ROW_SP = NA + NS + NP;

typedef short s16x8 __attribute__((ext_vector_type(8)));
typedef float f32x4 __attribute__((ext_vector_type(4)));
typedef unsigned short u16;

__device__ __forceinline__ float gelu_f(float x) {
  float x3 = x*x*x;
  return 0.5f*x*(1.0f + tanhf(0.7978845608028654f*(x + 0.044715f*x3)));
}
__device__ __forceinline__ u16 f2bf(float f) {
  unsigned u = __float_as_uint(f);
  u += 0x7fffu + ((u >> 16) & 1u);     // RNE
  return (u16)(u >> 16);
}
__device__ __forceinline__ float bf2f(u16 s) {
  return __uint_as_float((unsigned)s << 16);
}

// ---------------- W fragment packing (encoder only, K=256) ----------------
// Wp[((ks*8+cf)*64 + l)*8 + b] = bf16( W[ks*32 + (l>>4)*8 + b][cf*16 + (l&15)] )
__global__ void pack_w(const float* __restrict__ W, u16* __restrict__ Wp, int K) {
  int o = blockIdx.x*256 + threadIdx.x;
  if (o >= K*128) return;
  int b  = o & 7;
  int l  = (o >> 3) & 63;
  int cf = (o >> 9) & 7;
  int ks = o >> 12;
  int k   = ks*32 + (l >> 4)*8 + b;
  int col = cf*16 + (l & 15);
  Wp[o] = f2bf(W[k*128 + col]);
}

// ---------------- weight folding (f32, tiny) ----------------
// T0 = w0_pa @ w1_ap ; T1 = w0_ps @ w1_sp   (128x128 each)
__global__ __launch_bounds__(256) void fold_a(
    const float* __restrict__ A0, const float* __restrict__ B0,
    const float* __restrict__ A1, const float* __restrict__ B1,
    float* __restrict__ T)   // T[2][128*128]
{
  int o = blockIdx.x*256 + threadIdx.x;
  if (o >= 2*128*128) return;
  const float* A = (o < 128*128) ? A0 : A1;
  const float* B = (o < 128*128) ? B0 : B1;
  int p = o & (128*128-1);
  int r = p >> 7, c = p & 127;
  float acc = 0.f;
  #pragma unroll 4
  for (int k = 0; k < 128; ++k) acc = fmaf(A[r*128+k], B[k*128+c], acc);
  T[o] = acc;
}

// Wao = T0 @ out_w ; Wso = T1 @ out_w   (128x16 each)
__global__ __launch_bounds__(256) void fold_b(
    const float* __restrict__ T, const float* __restrict__ OW,
    float* __restrict__ WF)  // WF[2][128*16]
{
  int o = blockIdx.x*256 + threadIdx.x;
  if (o >= 2*128*16) return;
  const float* A = T + (o < 128*16 ? 0 : 128*128);
  int p = o & (128*16-1);
  int r = p >> 4, c = p & 15;
  float acc = 0.f;
  #pragma unroll 4
  for (int k = 0; k < 128; ++k) acc = fmaf(A[r*128+k], OW[k*16+c], acc);
  WF[o] = acc;
}

// ---------------- encoder GEMM: hp = gelu(x_p @ W + b), bf16 out ----------------
// wave = 16 rows x 128 cols; block = 4 waves = 64 rows; no LDS.
__global__ __launch_bounds__(256) void enc_gemm(
    const float* __restrict__ A, const u16* __restrict__ Wp,
    const float* __restrict__ bias, u16* __restrict__ C, int n)
{
  const int lane = threadIdx.x & 63;
  const int wv   = threadIdx.x >> 6;
  const int rowbase = blockIdx.x*64 + wv*16;
  const int m  = lane & 15;
  const int kq = lane >> 4;

  f32x4 acc[8];
  #pragma unroll
  for (int j = 0; j < 8; ++j) acc[j] = (f32x4){0.f,0.f,0.f,0.f};

  const int r0 = rowbase + m;
  const bool v0 = r0 < n;
  const float* Arow = A + (size_t)r0*256 + kq*8;

  #pragma unroll
  for (int ks = 0; ks < 8; ++ks) {
    s16x8 a0 = {0,0,0,0,0,0,0,0};
    if (v0) {
      float4 f = *(const float4*)(Arow + ks*32);
      float4 g = *(const float4*)(Arow + ks*32 + 4);
      a0[0]=(short)f2bf(f.x); a0[1]=(short)f2bf(f.y); a0[2]=(short)f2bf(f.z); a0[3]=(short)f2bf(f.w);
      a0[4]=(short)f2bf(g.x); a0[5]=(short)f2bf(g.y); a0[6]=(short)f2bf(g.z); a0[7]=(short)f2bf(g.w);
    }
    const s16x8* Wf = (const s16x8*)Wp + (size_t)ks*512 + lane;
    #pragma unroll
    for (int cf = 0; cf < 8; ++cf)
      acc[cf] = __builtin_amdgcn_mfma_f32_16x16x32_bf16(a0, Wf[cf*64], acc[cf], 0, 0, 0);
  }

  // D layout: col = lane&15, row-in-tile = (lane>>4)*4 + reg
  const int rb = rowbase + kq*4;
  #pragma unroll
  for (int cf = 0; cf < 8; ++cf) {
    const int col = cf*16 + m;
    const float bcol = bias[col];
    #pragma unroll
    for (int r = 0; r < 4; ++r) {
      const int row = rb + r;
      if (row < n) C[(size_t)row*128 + col] = f2bf(gelu_f(acc[cf][r] + bcol));
    }
  }
}

// ---------------- CSR build (global concatenated) ----------------
__global__ void deg_count_all(
    const int* __restrict__ pa, const int* __restrict__ ps,
    const int* __restrict__ ap, const int* __restrict__ sp,
    int* __restrict__ deg)
{
  int e = blockIdx.x*256 + threadIdx.x;
  if (e >= ETOT) return;
  int d, off;
  if (e < OFF_PS)      { d = pa[e];          off = 0; }
  else if (e < OFF_AP) { d = ps[e - OFF_PS]; off = ROW_PS; }
  else if (e < OFF_SP) { d = ap[e - OFF_AP]; off = ROW_AP; }
  else                 { d = sp[e - OFF_SP]; off = ROW_SP; }
  atomicAdd(&deg[off + d], 1);
}

__global__ __launch_bounds__(256) void scan_partial(const int* __restrict__ in, int n,
                                                    int* __restrict__ part) {
  __shared__ int red[4];
  int base = blockIdx.x*4096;
  int sum = 0;
  for (int i = threadIdx.x; i < 4096; i += 256) {
    int idx = base + i;
    sum += (idx < n) ? in[idx] : 0;
  }
  #pragma unroll
  for (int off = 32; off; off >>= 1) sum += __shfl_down(sum, off, 64);
  if ((threadIdx.x & 63) == 0) red[threadIdx.x >> 6] = sum;
  __syncthreads();
  if (threadIdx.x == 0) part[blockIdx.x] = red[0]+red[1]+red[2]+red[3];
}

__global__ __launch_bounds__(256) void scan_chunk(const int* __restrict__ in, int n,
    const int* __restrict__ part, int* __restrict__ out)
{
  int off0 = 0;
  for (int i = 0; i < (int)blockIdx.x; ++i) off0 += part[i];
  const int base = blockIdx.x*4096 + threadIdx.x*16;
  int loc[16]; int s = 0;
  #pragma unroll
  for (int j = 0; j < 16; ++j) {
    int idx = base + j;
    int v = (idx < n) ? in[idx] : 0;
    loc[j] = s; s += v;
  }
  __shared__ int ts[256];
  ts[threadIdx.x] = s; __syncthreads();
  for (int off = 1; off < 256; off <<= 1) {
    int t = (threadIdx.x >= off) ? ts[threadIdx.x - off] : 0;
    __syncthreads();
    ts[threadIdx.x] += t;
    __syncthreads();
  }
  int excl = off0 + ts[threadIdx.x] - s;
  #pragma unroll
  for (int j = 0; j < 16; ++j) {
    int idx = base + j;
    if (idx < n) out[idx] = excl + loc[j];
    if (idx == n-1) out[n] = excl + loc[j] + in[idx];
  }
}

// ciA valid for slots [0, OFF_AP); ciB is pre-shifted: ciB[slot] valid for [OFF_AP, ETOT)
__global__ void csr_fill_all(
    const int* __restrict__ pa_s, const int* __restrict__ pa_d,
    const int* __restrict__ ps_s, const int* __restrict__ ps_d,
    const int* __restrict__ ap_s, const int* __restrict__ ap_d,
    const int* __restrict__ sp_s, const int* __restrict__ sp_d,
    const int* __restrict__ rp, int* __restrict__ cur,
    int* __restrict__ ciA, int* __restrict__ ciB)
{
  int e = blockIdx.x*256 + threadIdx.x;
  if (e >= ETOT) return;
  int s, d, off;
  if (e < OFF_PS)      { s = pa_s[e];          d = pa_d[e];          off = 0; }
  else if (e < OFF_AP) { s = ps_s[e - OFF_PS]; d = ps_d[e - OFF_PS]; off = ROW_PS; }
  else if (e < OFF_SP) { s = ap_s[e - OFF_AP]; d = ap_d[e - OFF_AP]; off = ROW_AP; }
  else                 { s = sp_s[e - OFF_SP]; d = sp_d[e - OFF_SP]; off = ROW_SP; }
  int grow = off + d;
  int p = atomicAdd(&cur[grow], 1);
  int slot = rp[grow] + p;
  if (slot < OFF_AP) ciA[slot] = s; else ciB[slot] = s;
}

// ---------------- gather-mean (bf16 feat, f32 accum, bf16 out) ----------------
__device__ __forceinline__ void acc4(float* a, uint2 v) {
  a[0] += bf2f((u16)(v.x & 0xffff)); a[1] += bf2f((u16)(v.x >> 16));
  a[2] += bf2f((u16)(v.y & 0xffff)); a[3] += bf2f((u16)(v.y >> 16));
}

__global__ __launch_bounds__(256) void gather_mean(const u16* __restrict__ feat,
    const int* __restrict__ rp, const int* __restrict__ ci,
    u16* __restrict__ out, int n)
{
  int t = blockIdx.x*256 + threadIdx.x;
  int row = t >> 5, lane = t & 31;
  if (row >= n) return;
  int beg = rp[row], end = rp[row+1];
  float a[4] = {0.f,0.f,0.f,0.f};
  float b[4] = {0.f,0.f,0.f,0.f};
  int e = beg;
  for (; e + 1 < end; e += 2) {
    int s0 = ci[e], s1 = ci[e+1];
    uint2 u0 = *(const uint2*)(feat + (size_t)s0*128 + lane*4);
    uint2 u1 = *(const uint2*)(feat + (size_t)s1*128 + lane*4);
    acc4(a, u0); acc4(b, u1);
  }
  if (e < end) {
    uint2 u0 = *(const uint2*)(feat + (size_t)ci[e]*128 + lane*4);
    acc4(a, u0);
  }
  int d = end - beg;
  float r = 1.0f / (float)(d > 0 ? d : 1);
  uint2 o;
  o.x = (unsigned)f2bf((a[0]+b[0])*r) | ((unsigned)f2bf((a[1]+b[1])*r) << 16);
  o.y = (unsigned)f2bf((a[2]+b[2])*r) | ((unsigned)f2bf((a[3]+b[3])*r) << 16);
  *(uint2*)(out + (size_t)row*128 + lane*4) = o;
}

// ---------------- fused small GEMM: [NA+NS,128](bf16) @ [128,16](f32) -> f32 ----------------
__global__ __launch_bounds__(256) void head16(const u16* __restrict__ A,
    const float* __restrict__ WF,   // WF[0]=Wao (rows<NA), WF[1]=Wso
    float* __restrict__ O, int n)
{
  int t = blockIdx.x*256 + threadIdx.x;
  int row = t >> 4, col = t & 15;
  if (row >= n) return;
  const float* W = WF + (row < NA ? 0 : 128*16);
  const u16* Ar = A + (size_t)row*128;
  float acc = 0.f;
  #pragma unroll 8
  for (int k4 = 0; k4 < 32; ++k4) {
    uint2 v = *(const uint2*)(Ar + k4*4);
    acc = fmaf(bf2f((u16)(v.x & 0xffff)), W[(k4*4+0)*16+col], acc);
    acc = fmaf(bf2f((u16)(v.x >> 16)),    W[(k4*4+1)*16+col], acc);
    acc = fmaf(bf2f((u16)(v.y & 0xffff)), W[(k4*4+2)*16+col], acc);
    acc = fmaf(bf2f((u16)(v.y >> 16)),    W[(k4*4+3)*16+col], acc);
  }
  O[(size_t)row*16 + col] = acc;
}

// ---------------- final: out[p] = mean_ap(ma16) + mean_sp(ms16) + out_b ----------------
__global__ __launch_bounds__(256) void gather2_16(
    const float* __restrict__ f1, const int* __restrict__ rp1,
    const float* __restrict__ f2, const int* __restrict__ rp2,
    const int* __restrict__ ci, const float* __restrict__ ob,
    float* __restrict__ O, int n)
{
  int t = blockIdx.x*256 + threadIdx.x;
  int row = t >> 4, lane = t & 15;
  if (row >= n) return;

  float s1 = 0.f, s1b = 0.f;
  {
    int beg = rp1[row], end = rp1[row+1];
    int e = beg;
    for (; e + 1 < end; e += 2) {
      s1  += f1[(size_t)ci[e]  *16 + lane];
      s1b += f1[(size_t)ci[e+1]*16 + lane];
    }
    if (e < end) s1 += f1[(size_t)ci[e]*16 + lane];
    int d = end - beg;
    s1 = (s1 + s1b) / (float)(d > 0 ? d : 1);
  }
  float s2 = 0.f, s2b = 0.f;
  {
    int beg = rp2[row], end = rp2[row+1];
    int e = beg;
    for (; e + 1 < end; e += 2) {
      s2  += f2[(size_t)ci[e]  *16 + lane];
      s2b += f2[(size_t)ci[e+1]*16 + lane];
    }
    if (e < end) s2 += f2[(size_t)ci[e]*16 + lane];
    int d = end - beg;
    s2 = (s2 + s2b) / (float)(d > 0 ? d : 1);
  }
  O[(size_t)row*16 + lane] = s1 + s2 + ob[lane];
}

extern "C" void kernel_launch(void* const* d_in, const int* in_sizes, int n_in,
                              void* d_out, int out_size, void* d_ws, size_t ws_size,
                              hipStream_t stream)
{
  const float* x_p = (const float*)d_in[0];
  const int* pa_src=(const int*)d_in[3]; const int* pa_dst=(const int*)d_in[4];
  const int* ap_src=(const int*)d_in[5]; const int* ap_dst=(const int*)d_in[6];
  const int* ps_src=(const int*)d_in[7]; const int* ps_dst=(const int*)d_in[8];
  const int* sp_src=(const int*)d_in[9]; const int* sp_dst=(const int*)d_in[10];
  const float* ewp=(const float*)d_in[11]; const float* ebp=(const float*)d_in[12];
  const float* w0_pa=(const float*)d_in[17];
  const float* w0_ps=(const float*)d_in[19];
  const float* w1_ap=(const float*)d_in[22];
  const float* w1_sp=(const float*)d_in[24];
  const float* out_w=(const float*)d_in[25]; const float* out_b=(const float*)d_in[26];
  float* out = (float*)d_out;

  // ---- workspace layout ----
  char* wp = (char*)d_ws;
  auto alloc = [&](size_t bytes) { char* p = wp; wp += (bytes + 255) & ~(size_t)255; return p; };
  u16*   hp    = (u16*)alloc((size_t)NP*128*2);            // paper features (bf16)
  u16*   ga    = (u16*)alloc((size_t)(NA+NS)*128*2);       // ga || gs contiguous
  float* m16   = (float*)alloc((size_t)(NA+NS)*16*4);      // ma16 || ms16 contiguous
  u16*   wpk   = (u16*)alloc((size_t)256*128*2);           // packed encoder W
  float* Tfold = (float*)alloc((size_t)2*128*128*4);       // T0,T1
  float* WF    = (float*)alloc((size_t)2*128*16*4);        // Wao,Wso
  int*   deg   = (int*)alloc((size_t)2*NT*4);              // deg || cursor (one memset)
  int*   cursor= deg + NT;
  int*   rpG   = (int*)alloc((size_t)(NT+1)*4);
  int*   part  = (int*)alloc((size_t)64*4);

  // CSR column indices: one global array; fall back to d_out for the pa|ps half
  // (consumed before gather2_16 writes d_out) if ws is tight.
  int *ciA, *ciB;  // ciB pre-shifted so ciB[slot] is valid for slot in [OFF_AP, ETOT)
  size_t used = (size_t)(wp - (char*)d_ws);
  if (ws_size >= used + (size_t)ETOT*4) {
    int* base = (int*)alloc((size_t)ETOT*4);
    ciA = base; ciB = base;
  } else {
    int* bufB = (int*)alloc((size_t)(EAP+ESP)*4);  // ap|sp half must live in ws
    ciA = (int*)d_out;                             // pa|ps half: scratch in d_out
    ciB = bufB - OFF_AP;
  }

  // ---- weight prep ----
  pack_w<<<(256*128+255)/256,256,0,stream>>>(ewp, wpk, 256);
  fold_a<<<(2*128*128+255)/256,256,0,stream>>>(w0_pa, w1_ap, w0_ps, w1_sp, Tfold);
  fold_b<<<(2*128*16+255)/256,256,0,stream>>>(Tfold, out_w, WF);

  // ---- CSR build ----
  hipMemsetAsync(deg, 0, (size_t)2*NT*4, stream);
  deg_count_all<<<(ETOT+255)/256,256,0,stream>>>(pa_dst, ps_dst, ap_dst, sp_dst, deg);
  int nch = (NT + 4095)/4096;
  scan_partial<<<nch,256,0,stream>>>(deg, NT, part);
  scan_chunk  <<<nch,256,0,stream>>>(deg, NT, part, rpG);
  csr_fill_all<<<(ETOT+255)/256,256,0,stream>>>(pa_src, pa_dst, ps_src, ps_dst,
                                                ap_src, ap_dst, sp_src, sp_dst,
                                                rpG, cursor, ciA, ciB);

  // ---- paper encoder (the only live encoder) ----
  enc_gemm<<<(NP+63)/64,256,0,stream>>>(x_p, wpk, ebp, hp, NP);

  // ---- author+subject aggregation from papers (one launch; rows 0..NA+NS) ----
  gather_mean<<<(((size_t)(NA+NS)*32)+255)/256,256,0,stream>>>(hp, rpG, ciA, ga, NA+NS);

  // ---- folded transform: m16 = ga @ Wao | gs @ Wso  (f32 out) ----
  head16<<<(((size_t)(NA+NS)*16)+255)/256,256,0,stream>>>(ga, WF, m16, NA+NS);

  // ---- final paper aggregation + bias -> d_out ----
  gather2_16<<<(((size_t)NP*16)+255)/256,256,0,stream>>>(
      m16, rpG + ROW_AP,
      m16 + (size_t)NA*16, rpG + ROW_SP,
      ciB, out_b, out, NP);
}